// Round 4
// baseline (2838.300 us; speedup 1.0000x reference)
//
#include <hip/hip_runtime.h>
#include <stdint.h>

namespace {
constexpr int kB = 64, kT = 4096, kDin = 64, kDe = 24, kH = 128;
constexpr int kChunk = 256;              // e-steps staged per LDS chunk
constexpr int kNChunk = kT / kChunk;     // 16
constexpr int kEB = kChunk * 12;         // uints per e chunk buffer (3072)
constexpr int kE0 = 128;                 // e chunks start after 2x h parity bufs

typedef __attribute__((ext_vector_type(2))) _Float16 half2_t;
union H2U { uint32_t u; half2_t h; _Float16 s[2]; };

__device__ __forceinline__ float rcp_fast(float x){
#if __has_builtin(__builtin_amdgcn_rcpf)
  return __builtin_amdgcn_rcpf(x);
#else
  return 1.0f / x;
#endif
}
__device__ __forceinline__ float sigmoid_f(float x){
  return rcp_fast(1.0f + __expf(-x));
}
__device__ __forceinline__ float tanh_f(float x){
  return 1.0f - 2.0f * rcp_fast(1.0f + __expf(2.0f * x));
}
__device__ __forceinline__ half2_t fma2(uint32_t a, uint32_t b, half2_t c){
  H2U ua; ua.u = a; H2U ub; ub.u = b;
#if __has_builtin(__builtin_elementwise_fma)
  return __builtin_elementwise_fma(ua.h, ub.h, c);
#else
  return ua.h * ub.h + c;
#endif
}
__device__ __forceinline__ float h2sum(half2_t v){
  H2U u; u.h = v; return (float)u.s[0] + (float)u.s[1];
}
__device__ __forceinline__ uint32_t pack2(float lo, float hi){
  H2U u; u.s[0] = (_Float16)lo; u.s[1] = (_Float16)hi; return u.u;
}
} // namespace

// Kernel 1 (parallel): e[b,t,:] = sigmoid(x[b,t,:] @ W_emb + b_emb) packed f16.
__global__ __launch_bounds__(256) void emb_kernel(
    const float* __restrict__ x, const float* __restrict__ W,
    const float* __restrict__ bias, uint32_t* __restrict__ e_out)
{
  int r = blockIdx.x * blockDim.x + threadIdx.x;
  if (r >= kB * kT) return;
  const float4* xr = (const float4*)(x + (size_t)r * kDin);
  float acc[kDe];
#pragma unroll
  for (int k = 0; k < kDe; ++k) acc[k] = bias[k];
#pragma unroll 4
  for (int d4 = 0; d4 < kDin / 4; ++d4){
    float4 xv = xr[d4];
    const float* w0 = W + (size_t)(d4 * 4) * kDe;
#pragma unroll
    for (int k = 0; k < kDe; ++k) acc[k] += xv.x * w0[k];
#pragma unroll
    for (int k = 0; k < kDe; ++k) acc[k] += xv.y * w0[kDe + k];
#pragma unroll
    for (int k = 0; k < kDe; ++k) acc[k] += xv.z * w0[2 * kDe + k];
#pragma unroll
    for (int k = 0; k < kDe; ++k) acc[k] += xv.w * w0[3 * kDe + k];
  }
  uint32_t p[12];
#pragma unroll
  for (int k = 0; k < 12; ++k)
    p[k] = pack2(sigmoid_f(acc[2 * k]), sigmoid_f(acc[2 * k + 1]));
  uint4* dst = (uint4*)(e_out + (size_t)r * 12);
  dst[0] = make_uint4(p[0], p[1], p[2],  p[3]);
  dst[1] = make_uint4(p[4], p[5], p[6],  p[7]);
  dst[2] = make_uint4(p[8], p[9], p[10], p[11]);
}

// Kernel 2: one block (512 threads, 8 waves = 2 waves/SIMD) per batch element.
// Lane l: gate g = l>>4 (f,i,g,o), unit j = w*16 + (l&15). Each thread computes
// one full 152-wide gate dot (76 pk_fma, 4 acc chains) + its own nonlinearity;
// unit j's 4 gates are gathered in-wave via shfl_xor(16/32); c/h update on g0
// lanes. One barrier per step. e staged in double-buffered 256-step LDS chunks.
__global__ __launch_bounds__(512, 2) void lstm_kernel(
    const uint32_t* __restrict__ e_ws,
    const float* __restrict__ W_f, const float* __restrict__ b_f,
    const float* __restrict__ W_i, const float* __restrict__ b_i,
    const float* __restrict__ W_c, const float* __restrict__ b_c,
    const float* __restrict__ W_o, const float* __restrict__ b_o,
    const float* __restrict__ W_out, const float* __restrict__ b_out,
    float* __restrict__ out)
{
  // smem (uints): [0,64) h parity0 (128 f16) | [64,128) h parity1 |
  //               [128,3200) e chunk buf0 | [3200,6272) e chunk buf1
  __shared__ __align__(16) uint32_t smem[kE0 + 2 * kEB];
  __shared__ float red[8];

  const int b  = blockIdx.x;
  const int t0 = threadIdx.x;
  const int w  = t0 >> 6;
  const int l  = t0 & 63;
  const int g  = l >> 4;           // 0=f 1=i 2=g 3=o
  const int jj = l & 15;
  const int j  = w * 16 + jj;      // hidden unit owned (for gate g)
  const bool isG = (g == 2);

  const float* Wg = (g & 2) ? ((g & 1) ? W_o : W_c) : ((g & 1) ? W_i : W_f);
  const float  bj = ((g & 2) ? ((g & 1) ? b_o : b_c) : ((g & 1) ? b_i : b_f))[j];
  const float  m1 = isG ? 2.0f : 1.0f;   // pre-scale for tanh-as-sigmoid
  const float  m2 = isG ? 2.0f : 1.0f;   // post-scale
  const float  bb = isG ? -1.0f : 0.0f;  // post-bias

  // pack this thread's gate column (rows 0..151 -> 76 f16 pairs) into regs
  uint32_t wreg[76];
#pragma unroll
  for (int p = 0; p < 76; ++p)
    wreg[p] = pack2(Wg[(2 * p) * kH + j], Wg[(2 * p + 1) * kH + j]);

  const uint4* e_rows = (const uint4*)e_ws;   // 3 uint4 per (b,t) row
  uint4 pre0, pre1;
  const size_t bbase = (size_t)b * kT * 3;

  // chunk 0 -> ebuf0 (768 uint4)
  {
    const uint4* src = e_rows + bbase;
    uint4* dst = (uint4*)&smem[kE0];
    uint4 v0 = src[t0]; dst[t0] = v0;
    if (t0 < 256){ uint4 v1 = src[512 + t0]; dst[512 + t0] = v1; }
  }
  if (t0 < 64) smem[t0] = 0u;      // h parity0 = 0
  float cst = 0.0f, h_last = 0.0f;
  __syncthreads();

#pragma unroll 1
  for (int cc = 0; cc < kNChunk; ++cc){
    const int ebi = cc & 1;
    if (cc + 1 < kNChunk){         // issue next chunk's loads (held in regs)
      const uint4* src = e_rows + bbase + (size_t)(cc + 1) * kChunk * 3;
      pre0 = src[t0];
      if (t0 < 256) pre1 = src[512 + t0];
    }
    const int ebase0 = kE0 + ebi * kEB;

#pragma unroll 1
    for (int s = 0; s < kChunk; ++s){
      const int t   = cc * kChunk + s;
      const int cur = t & 1, nxt = cur ^ 1;
      const int eb  = ebase0 + s * 12;
      const int hb  = cur * 64;

      // z = [e(12 uints from chunk); h(16 uint4 from parity buf)] - all
      // wave-uniform addresses (LDS broadcast).
      uint4 q[19];
#pragma unroll
      for (int k = 0; k < 3; ++k)  q[k]     = *(const uint4*)&smem[eb + 4 * k];
#pragma unroll
      for (int m = 0; m < 16; ++m) q[3 + m] = *(const uint4*)&smem[hb + 4 * m];

      // 76 pk_fma, 4 independent f16x2 accumulator chains
      half2_t a0 = (half2_t)0, a1 = (half2_t)0, a2 = (half2_t)0, a3 = (half2_t)0;
#pragma unroll
      for (int k = 0; k < 19; ++k){
        uint4 qq = q[k];
        a0 = fma2(qq.x, wreg[4 * k + 0], a0);
        a1 = fma2(qq.y, wreg[4 * k + 1], a1);
        a2 = fma2(qq.z, wreg[4 * k + 2], a2);
        a3 = fma2(qq.w, wreg[4 * k + 3], a3);
      }
      float sgate = h2sum(a0 + a1) + h2sum(a2 + a3);

      // branchless nonlinearity: sigmoid for f,i,o; tanh = 2*sig(2x)-1 for g
      float arg = (sgate + bj) * m1;
      float v   = fmaf(rcp_fast(1.0f + __expf(-arg)), m2, bb);

      // gather unit j's 4 gates into its g0 lane (lane-xor 16/32, depth 2)
      float u  = __shfl_xor(v, 16, 64);   // g0 gets i ; g2 gets o
      float w1 = __shfl_xor(v, 32, 64);   // g0 gets tanh-g
      float w2 = __shfl_xor(u, 32, 64);   // g0 gets o

      if (g == 0){
        cst    = fmaf(cst, v, u * w1);    // c = c*f + i*g
        h_last = tanh_f(cst) * w2;        // h = tanh(c) * o
        ((_Float16*)smem)[nxt * 128 + j] = (_Float16)h_last;
      }
      __syncthreads();
    }

    if (cc + 1 < kNChunk){         // commit next chunk into the other buffer
      uint4* dst = (uint4*)&smem[kE0 + (ebi ^ 1) * kEB];
      dst[t0] = pre0;
      if (t0 < 256) dst[512 + t0] = pre1;
      __syncthreads();
    }
  }

  // epilogue: out[b] = sigmoid(h_T @ W_out + b_out)
  float partial = (g == 0) ? h_last * W_out[j] : 0.0f;
#pragma unroll
  for (int off = 1; off <= 32; off <<= 1) partial += __shfl_xor(partial, off, 64);
  if (l == 0) red[w] = partial;
  __syncthreads();
  if (t0 == 0){
    float acc = b_out[0];
#pragma unroll
    for (int k = 0; k < 8; ++k) acc += red[k];
    out[b] = sigmoid_f(acc);
  }
}

extern "C" void kernel_launch(void* const* d_in, const int* in_sizes, int n_in,
                              void* d_out, int out_size, void* d_ws, size_t ws_size,
                              hipStream_t stream){
  const float* x     = (const float*)d_in[0];
  const float* W_emb = (const float*)d_in[1];
  const float* b_emb = (const float*)d_in[2];
  const float* W_f   = (const float*)d_in[3];
  const float* b_f   = (const float*)d_in[4];
  const float* W_i   = (const float*)d_in[5];
  const float* b_i   = (const float*)d_in[6];
  const float* W_c   = (const float*)d_in[7];
  const float* b_c   = (const float*)d_in[8];
  const float* W_o   = (const float*)d_in[9];
  const float* b_o   = (const float*)d_in[10];
  const float* W_out = (const float*)d_in[11];
  const float* b_out = (const float*)d_in[12];
  float* out = (float*)d_out;
  uint32_t* e_ws = (uint32_t*)d_ws;    // B*T*12*4 = 12.6 MB

  const int rows = kB * kT;
  emb_kernel<<<(rows + 255) / 256, 256, 0, stream>>>(x, W_emb, b_emb, e_ws);
  lstm_kernel<<<kB, 512, 0, stream>>>(e_ws, W_f, b_f, W_i, b_i, W_c, b_c,
                                      W_o, b_o, W_out, b_out, out);
}

// Round 5
// 2106.028 us; speedup vs baseline: 1.3477x; 1.3477x over previous
//
#include <hip/hip_runtime.h>
#include <stdint.h>

namespace {
constexpr int kB = 64, kT = 4096, kDin = 64, kDe = 24, kH = 128;
constexpr int kChunk = 128;             // e-steps per LDS chunk
constexpr int kNCh = kT / kChunk;       // 32
constexpr int kRowU = 16;               // uints per padded e row (24 f16 + 8 zero)
constexpr int kEB = kChunk * kRowU;     // 2048 uints per chunk buffer
constexpr int kE0 = 128;                // e chunks start after 2x h parity bufs (2x64 uints)

typedef __attribute__((ext_vector_type(8))) _Float16 frag8;   // MFMA A/B (4 VGPR)
typedef __attribute__((ext_vector_type(4))) float fragC;      // MFMA C/D
typedef __attribute__((ext_vector_type(2))) _Float16 half2_t;
union H2U { uint32_t u; half2_t h; _Float16 s[2]; };

__device__ __forceinline__ float rcp_fast(float x){
#if __has_builtin(__builtin_amdgcn_rcpf)
  return __builtin_amdgcn_rcpf(x);
#else
  return 1.0f / x;
#endif
}
__device__ __forceinline__ float sigmoid_f(float x){
  return rcp_fast(1.0f + __expf(-x));
}
__device__ __forceinline__ float tanh_f(float x){
  return 1.0f - 2.0f * rcp_fast(1.0f + __expf(2.0f * x));
}
__device__ __forceinline__ uint32_t pack2(float lo, float hi){
  H2U u; u.s[0] = (_Float16)lo; u.s[1] = (_Float16)hi; return u.u;
}
} // namespace

// Kernel 1 (parallel): e[b,t,:] = sigmoid(x[b,t,:] @ W_emb + b_emb), packed f16,
// rows padded to 32 f16 (last 8 = 0) so MFMA A k-block 0 reads are clean b128.
__global__ __launch_bounds__(256) void emb_kernel(
    const float* __restrict__ x, const float* __restrict__ W,
    const float* __restrict__ bias, uint32_t* __restrict__ e_out)
{
  int r = blockIdx.x * blockDim.x + threadIdx.x;
  if (r >= kB * kT) return;
  const float4* xr = (const float4*)(x + (size_t)r * kDin);
  float acc[kDe];
#pragma unroll
  for (int k = 0; k < kDe; ++k) acc[k] = bias[k];
#pragma unroll 4
  for (int d4 = 0; d4 < kDin / 4; ++d4){
    float4 xv = xr[d4];
    const float* w0 = W + (size_t)(d4 * 4) * kDe;
#pragma unroll
    for (int k = 0; k < kDe; ++k) acc[k] += xv.x * w0[k];
#pragma unroll
    for (int k = 0; k < kDe; ++k) acc[k] += xv.y * w0[kDe + k];
#pragma unroll
    for (int k = 0; k < kDe; ++k) acc[k] += xv.z * w0[2 * kDe + k];
#pragma unroll
    for (int k = 0; k < kDe; ++k) acc[k] += xv.w * w0[3 * kDe + k];
  }
  uint32_t p[12];
#pragma unroll
  for (int k = 0; k < 12; ++k)
    p[k] = pack2(sigmoid_f(acc[2 * k]), sigmoid_f(acc[2 * k + 1]));
  uint4* dst = (uint4*)(e_out + (size_t)r * kRowU);
  dst[0] = make_uint4(p[0], p[1], p[2],  p[3]);
  dst[1] = make_uint4(p[4], p[5], p[6],  p[7]);
  dst[2] = make_uint4(p[8], p[9], p[10], p[11]);
  dst[3] = make_uint4(0u, 0u, 0u, 0u);
}

// Kernel 2: one block (512 thr, 8 waves) per batch element. Gates via MFMA:
// z[1x160] (e 0..23, pad, h at k=32..159) x W[160x512]. Wave w owns units
// u0=w*16..+15, 4 gate tiles (f,i,g,o) x 5 K-blocks = 20 MFMA/step. B-frags
// in VGPRs; A-frags from LDS (uniform per quad -> broadcast). C/D layout:
// col=lane&15, row=quad*4+reg -> row 0 (the chain) lives in lanes 0..15 reg 0;
// all 4 gates of unit u0+col in the SAME lane -> in-lane c/h update, no shfl.
// One barrier per step.
__global__ __launch_bounds__(512, 2) void lstm_kernel(
    const uint32_t* __restrict__ e_ws,
    const float* __restrict__ W_f, const float* __restrict__ b_f,
    const float* __restrict__ W_i, const float* __restrict__ b_i,
    const float* __restrict__ W_c, const float* __restrict__ b_c,
    const float* __restrict__ W_o, const float* __restrict__ b_o,
    const float* __restrict__ W_out, const float* __restrict__ b_out,
    float* __restrict__ out)
{
  // smem (uints): [0,64) h parity0 (128 f16) | [64,128) h parity1 |
  //               [128,128+kEB) e chunk buf0 | [..,+kEB) e chunk buf1
  __shared__ __align__(16) uint32_t sh[kE0 + 2 * kEB];
  __shared__ float red[8];

  const int b  = blockIdx.x;
  const int t0 = threadIdx.x;
  const int w  = t0 >> 6;
  const int l  = t0 & 63;
  const int q  = l >> 4;           // quad
  const int cl = l & 15;           // column within tile
  const int u  = w * 16 + cl;      // hidden unit of this lane's column

  const float* Wg[4] = {W_f, W_i, W_c, W_o};
  const float biasv[4] = {b_f[u], b_i[u], b_c[u], b_o[u]};

  // B-frags: Bf[gate][kblock]; lane holds B[k = kb*32 + q*8 + j][n = u].
  // z-row k maps to W row: kb==0 -> k<24 = W row k (else 0 pad);
  // kb>=1 -> W row (k-8) (h starts at z k=32 <-> W row 24).
  frag8 Bf[4][5];
#pragma unroll
  for (int g = 0; g < 4; ++g){
#pragma unroll
    for (int kb = 0; kb < 5; ++kb){
#pragma unroll
      for (int j = 0; j < 8; ++j){
        int zk = kb * 32 + q * 8 + j;
        float wv = 0.0f;
        if (kb == 0){ if (zk < kDe) wv = Wg[g][zk * kH + u]; }
        else        { wv = Wg[g][(zk - 8) * kH + u]; }
        Bf[g][kb][j] = (_Float16)wv;
      }
    }
  }

  const float bsel = (l < 16) ? 1.0f : 0.0f;   // only row-0 lanes get bias

  // chunk 0 -> ebuf0 (kEB uints = 512 x uint4)
  const uint4* e_rows = (const uint4*)e_ws;    // 4 uint4 per (b,t) row
  const size_t bbase = (size_t)b * kT * 4;
  uint4 pre;
  {
    const uint4* src = e_rows + bbase;
    ((uint4*)&sh[kE0])[t0] = src[t0];
  }
  if (t0 < 64) sh[t0] = 0u;        // h parity0 = 0
  float cst = 0.0f, h_last = 0.0f;
  __syncthreads();

#pragma unroll 1
  for (int cc = 0; cc < kNCh; ++cc){
    const int ebi = cc & 1;
    if (cc + 1 < kNCh){            // issue next chunk's loads (held in regs)
      const uint4* src = e_rows + bbase + (size_t)(cc + 1) * kChunk * 4;
      pre = src[t0];
    }
    const int ebase = kE0 + ebi * kEB;

#pragma unroll 1
    for (int s = 0; s < kChunk; ++s){
      const int t   = cc * kChunk + s;
      const int cur = t & 1, nxt = cur ^ 1;

      // A-frags: kb0 from e row (padded), kb1..4 from h parity buffer.
      frag8 A[5];
      A[0] = *(const frag8*)&sh[ebase + s * kRowU + q * 4];
      const uint32_t* hcur = &sh[cur * 64];
#pragma unroll
      for (int kb = 1; kb < 5; ++kb)
        A[kb] = *(const frag8*)&hcur[(kb - 1) * 16 + q * 4];

      fragC acc[4];
#pragma unroll
      for (int g = 0; g < 4; ++g){
        acc[g][0] = bsel * biasv[g];
        acc[g][1] = 0.0f; acc[g][2] = 0.0f; acc[g][3] = 0.0f;
      }
#pragma unroll
      for (int kb = 0; kb < 5; ++kb){
#pragma unroll
        for (int g = 0; g < 4; ++g)
          acc[g] = __builtin_amdgcn_mfma_f32_16x16x32_f16(A[kb], Bf[g][kb],
                                                          acc[g], 0, 0, 0);
      }

      if (l < 16){                 // row 0 = the real chain
        float f  = sigmoid_f(acc[0][0]);
        float ig = sigmoid_f(acc[1][0]);
        float gg = tanh_f(acc[2][0]);
        float og = sigmoid_f(acc[3][0]);
        cst    = fmaf(cst, f, ig * gg);
        h_last = tanh_f(cst) * og;
        ((_Float16*)&sh[nxt * 64])[u] = (_Float16)h_last;
      }
      __syncthreads();
    }

    if (cc + 1 < kNCh){            // commit next chunk into the other buffer
      ((uint4*)&sh[kE0 + (ebi ^ 1) * kEB])[t0] = pre;
      __syncthreads();
    }
  }

  // epilogue: out[b] = sigmoid(h_T @ W_out + b_out)
  float partial = (l < 16) ? h_last * W_out[u] : 0.0f;
#pragma unroll
  for (int off = 8; off >= 1; off >>= 1) partial += __shfl_xor(partial, off, 64);
  if (l == 0) red[w] = partial;
  __syncthreads();
  if (t0 == 0){
    float acc = b_out[0];
#pragma unroll
    for (int k = 0; k < 8; ++k) acc += red[k];
    out[b] = sigmoid_f(acc);
  }
}

extern "C" void kernel_launch(void* const* d_in, const int* in_sizes, int n_in,
                              void* d_out, int out_size, void* d_ws, size_t ws_size,
                              hipStream_t stream){
  const float* x     = (const float*)d_in[0];
  const float* W_emb = (const float*)d_in[1];
  const float* b_emb = (const float*)d_in[2];
  const float* W_f   = (const float*)d_in[3];
  const float* b_f   = (const float*)d_in[4];
  const float* W_i   = (const float*)d_in[5];
  const float* b_i   = (const float*)d_in[6];
  const float* W_c   = (const float*)d_in[7];
  const float* b_c   = (const float*)d_in[8];
  const float* W_o   = (const float*)d_in[9];
  const float* b_o   = (const float*)d_in[10];
  const float* W_out = (const float*)d_in[11];
  const float* b_out = (const float*)d_in[12];
  float* out = (float*)d_out;
  uint32_t* e_ws = (uint32_t*)d_ws;    // B*T*16*4 = 16.8 MB

  const int rows = kB * kT;
  emb_kernel<<<(rows + 255) / 256, 256, 0, stream>>>(x, W_emb, b_emb, e_ws);
  lstm_kernel<<<kB, 512, 0, stream>>>(e_ws, W_f, b_f, W_i, b_i, W_c, b_c,
                                      W_o, b_o, W_out, b_out, out);
}

// Round 7
// 1814.675 us; speedup vs baseline: 1.5641x; 1.1606x over previous
//
#include <hip/hip_runtime.h>
#include <stdint.h>

namespace {
constexpr int kB = 64, kT = 4096, kDin = 64, kDe = 24, kH = 128;
constexpr int kCh = 16;                 // steps per pre-chunk
constexpr int kNCh = kT / kCh;          // 256 chunks
constexpr int kRowU = 16;               // uints per padded e row (24 f16 + 8 zero)

typedef __attribute__((ext_vector_type(8))) _Float16 frag8;   // f16 MFMA A/B
typedef __attribute__((ext_vector_type(4))) float v4f;        // MFMA C/D
typedef __attribute__((ext_vector_type(8))) int v8i;          // fp8 MFMA A/B
union H2U { uint32_t u; _Float16 s[2]; };

__device__ __forceinline__ float rcp_fast(float x){
#if __has_builtin(__builtin_amdgcn_rcpf)
  return __builtin_amdgcn_rcpf(x);
#else
  return 1.0f / x;
#endif
}
__device__ __forceinline__ float sigmoid_f(float x){
  return rcp_fast(1.0f + __expf(-x));
}
__device__ __forceinline__ float tanh_f(float x){
  return 1.0f - 2.0f * rcp_fast(1.0f + __expf(2.0f * x));
}
__device__ __forceinline__ uint32_t pack2(float lo, float hi){
  H2U u; u.s[0] = (_Float16)lo; u.s[1] = (_Float16)hi; return u.u;
}
__device__ __forceinline__ uint32_t sw_fp8(float x){   // fallback e4m3 encode
  union{float f; uint32_t u;} v; v.f = x;
  uint32_t s = (v.u >> 24) & 0x80u;
  float a = fabsf(x);
  if (a < 0.0009765625f) return s;
  if (a > 448.0f) a = 448.0f;
  int e; float m = frexpf(a, &e);       // a = m * 2^e, m in [0.5,1)
  int E = e - 1 + 7;
  uint32_t bits;
  if (E <= 0){
    int q = (int)(a * 512.0f + 0.5f); if (q > 7) q = 7; bits = (uint32_t)q;
  } else {
    int q = (int)(m * 16.0f + 0.5f);
    if (q == 16){ q = 8; ++E; }
    if (E > 15) { E = 15; q = 14; }
    bits = ((uint32_t)E << 3) | ((uint32_t)q & 7u);
  }
  return s | bits;
}
// pack two floats as fp8 e4m3 into low/high half of a word (HI is immediate)
template <bool HI>
__device__ __forceinline__ uint32_t fp8pair(float a, float b, uint32_t old){
#if __has_builtin(__builtin_amdgcn_cvt_pk_fp8_f32)
  return (uint32_t)__builtin_amdgcn_cvt_pk_fp8_f32(a, b, (int)old, HI);
#else
  uint32_t p = sw_fp8(a) | (sw_fp8(b) << 8);
  return HI ? ((old & 0x0000ffffu) | (p << 16)) : ((old & 0xffff0000u) | p);
#endif
}
} // namespace

// Kernel 1 (parallel): e[b,t,:] = sigmoid(x[b,t,:] @ W_emb + b_emb), packed f16,
// rows padded to 32 f16 (last 8 = 0).
__global__ __launch_bounds__(256) void emb_kernel(
    const float* __restrict__ x, const float* __restrict__ W,
    const float* __restrict__ bias, uint32_t* __restrict__ e_out)
{
  int r = blockIdx.x * blockDim.x + threadIdx.x;
  if (r >= kB * kT) return;
  const float4* xr = (const float4*)(x + (size_t)r * kDin);
  float acc[kDe];
#pragma unroll
  for (int k = 0; k < kDe; ++k) acc[k] = bias[k];
#pragma unroll 4
  for (int d4 = 0; d4 < kDin / 4; ++d4){
    float4 xv = xr[d4];
    const float* w0 = W + (size_t)(d4 * 4) * kDe;
#pragma unroll
    for (int k = 0; k < kDe; ++k) acc[k] += xv.x * w0[k];
#pragma unroll
    for (int k = 0; k < kDe; ++k) acc[k] += xv.y * w0[kDe + k];
#pragma unroll
    for (int k = 0; k < kDe; ++k) acc[k] += xv.z * w0[2 * kDe + k];
#pragma unroll
    for (int k = 0; k < kDe; ++k) acc[k] += xv.w * w0[3 * kDe + k];
  }
  uint32_t p[12];
#pragma unroll
  for (int k = 0; k < 12; ++k)
    p[k] = pack2(sigmoid_f(acc[2 * k]), sigmoid_f(acc[2 * k + 1]));
  uint4* dst = (uint4*)(e_out + (size_t)r * kRowU);
  dst[0] = make_uint4(p[0], p[1], p[2],  p[3]);
  dst[1] = make_uint4(p[4], p[5], p[6],  p[7]);
  dst[2] = make_uint4(p[8], p[9], p[10], p[11]);
  dst[3] = make_uint4(0u, 0u, 0u, 0u);
}

// Kernel 2: one block (512 thr, 8 waves) per batch chain.
// Serial h-GEMM via MX-fp8 scaled MFMA 16x16x128: 4 instr/wave/step (32 total).
// Wave w owns units u = w*16+(l&15) for all 4 gates. A rows are all the
// broadcast h vector, so acc[g][0] is valid in EVERY lane. e-part + bias
// precomputed per 16-step chunk into LDS via f16 MFMA (A rows = steps).
__global__ __launch_bounds__(512, 1) void lstm_kernel(
    const uint32_t* __restrict__ e_ws,
    const float* __restrict__ W_f, const float* __restrict__ b_f,
    const float* __restrict__ W_i, const float* __restrict__ b_i,
    const float* __restrict__ W_c, const float* __restrict__ b_c,
    const float* __restrict__ W_o, const float* __restrict__ b_o,
    const float* __restrict__ W_out, const float* __restrict__ b_out,
    float* __restrict__ out)
{
  __shared__ __align__(16) _Float16 preh[2 * kCh * 512];  // 32 KB pre (incl bias)
  __shared__ __align__(16) uint32_t elds[kCh * kRowU];    // 1 KB e chunk (f16)
  __shared__ __align__(16) uint32_t hfp8[2 * 32];         // 2 x 128 B h (fp8 x64)
  __shared__ float red[8];

  const int b  = blockIdx.x;
  const int t0 = threadIdx.x;
  const int w  = t0 >> 6;
  const int l  = t0 & 63;
  const int q  = l >> 4;
  const int cl = l & 15;
  const int u  = w * 16 + cl;      // hidden unit owned

  const float* Wg[4] = {W_f, W_i, W_c, W_o};

  // fp8 B-frags for the h-GEMM: B[k][n]: n = u, k = q*32 + r*4 + byte,
  // W row = 24 + k, stored value = w*64 with E8M0 scale 2^-6.
  v8i B8[4];
#pragma unroll
  for (int g = 0; g < 4; ++g){
#pragma unroll
    for (int r = 0; r < 8; ++r){
      const float* col = Wg[g] + (size_t)(24 + q * 32 + r * 4) * kH + u;
      uint32_t reg = fp8pair<false>(col[0] * 64.0f, col[kH] * 64.0f, 0u);
      reg = fp8pair<true>(col[2 * kH] * 64.0f, col[3 * kH] * 64.0f, reg);
      B8[g][r] = (int)reg;
    }
  }

  // f16 B-frags for the pre-GEMM (e-part, K=32 padded from 24): B[k][n]=Wg[k][u]
  frag8 Bp[4];
  float biasC[4] = {b_f[u], b_i[u], b_c[u], b_o[u]};
#pragma unroll
  for (int g = 0; g < 4; ++g){
#pragma unroll
    for (int j = 0; j < 8; ++j){
      int k = q * 8 + j;
      Bp[g][j] = (_Float16)((k < kDe) ? Wg[g][(size_t)k * kH + u] : 0.0f);
    }
  }

  const uint4* e4 = (const uint4*)e_ws;          // 4 uint4 per (b,t) row
  const size_t bbase = (size_t)b * kT * 4;

  auto do_pregemm = [&](int buf){
    frag8 Ae = *(const frag8*)&elds[cl * kRowU + q * 4];  // A[step=cl][k=q*8+j]
#pragma unroll
    for (int g = 0; g < 4; ++g){
      v4f c; c[0] = biasC[g]; c[1] = biasC[g]; c[2] = biasC[g]; c[3] = biasC[g];
      v4f d = __builtin_amdgcn_mfma_f32_16x16x32_f16(Ae, Bp[g], c, 0, 0, 0);
#pragma unroll
      for (int r = 0; r < 4; ++r)
        preh[buf * (kCh * 512) + (q * 4 + r) * 512 + g * 128 + u] = (_Float16)d[r];
    }
  };

  // startup: e chunk 0 -> elds; pre chunk 0; h = 0
  uint4 pre4;
  if (t0 < 64) pre4 = e4[bbase + t0];
  if (t0 < 32) hfp8[t0] = 0u;
  if (t0 < 64) ((uint4*)elds)[t0] = pre4;
  __syncthreads();
  do_pregemm(0);
  if (t0 < 64 && kNCh > 1) pre4 = e4[bbase + (size_t)kCh * 4 + t0];  // prefetch c1
  __syncthreads();

  float cst = 0.0f, h_last = 0.0f;

#pragma unroll 1
  for (int cc = 0; cc < kNCh; ++cc){
    const int pbuf = cc & 1;

#pragma unroll 1
    for (int s = 0; s < kCh; ++s){
      const int t   = cc * kCh + s;
      const int cur = t & 1, nxt = cur ^ 1;

      // A: the 32 h-bytes for this lane's k-quad (uniform per quad -> broadcast)
      const uint32_t* hb = &hfp8[cur * 32];
      uint4 lo  = *(const uint4*)(hb + q * 8);
      uint4 hi4 = *(const uint4*)(hb + q * 8 + 4);
      v8i A;
      A[0] = (int)lo.x;  A[1] = (int)lo.y;  A[2] = (int)lo.z;  A[3] = (int)lo.w;
      A[4] = (int)hi4.x; A[5] = (int)hi4.y; A[6] = (int)hi4.z; A[7] = (int)hi4.w;

      const _Float16* pb = &preh[pbuf * (kCh * 512) + s * 512 + w * 16 + cl];
      v4f acc[4];
#pragma unroll
      for (int g = 0; g < 4; ++g){
        v4f c; c[0] = (float)pb[g * 128]; c[1] = 0.0f; c[2] = 0.0f; c[3] = 0.0f;
        acc[g] = __builtin_amdgcn_mfma_scale_f32_16x16x128_f8f6f4(
                     A, B8[g], c, 0, 0, 0, 121, 0, 121);
      }

      // every lane holds its unit's 4 gate pre-activations in acc[g][0]
      float f  = sigmoid_f(acc[0][0]);
      float ig = sigmoid_f(acc[1][0]);
      float gg = tanh_f(acc[2][0]);
      float og = sigmoid_f(acc[3][0]);
      cst    = fmaf(cst, f, ig * gg);
      h_last = tanh_f(cst) * og;
      if (l < 16){
        uint32_t byte = fp8pair<false>(h_last * 64.0f, h_last * 64.0f, 0u) & 0xffu;
        ((uint8_t*)&hfp8[nxt * 32])[u] = (uint8_t)byte;
      }
      __syncthreads();
    }

    if (cc + 1 < kNCh){
      // commit prefetched e chunk, run pre-GEMM for chunk cc+1, prefetch cc+2
      if (t0 < 64) ((uint4*)elds)[t0] = pre4;
      __syncthreads();
      do_pregemm((cc + 1) & 1);
      if (t0 < 64 && cc + 2 < kNCh)
        pre4 = e4[bbase + (size_t)(cc + 2) * kCh * 4 + t0];
      __syncthreads();
    }
  }

  // epilogue: out[b] = sigmoid(h_T @ W_out + b_out)
  float partial = (l < 16) ? h_last * W_out[u] : 0.0f;
#pragma unroll
  for (int off = 1; off <= 32; off <<= 1) partial += __shfl_xor(partial, off, 64);
  if (l == 0) red[w] = partial;
  __syncthreads();
  if (t0 == 0){
    float acc = b_out[0];
#pragma unroll
    for (int k = 0; k < 8; ++k) acc += red[k];
    out[b] = sigmoid_f(acc);
  }
}

extern "C" void kernel_launch(void* const* d_in, const int* in_sizes, int n_in,
                              void* d_out, int out_size, void* d_ws, size_t ws_size,
                              hipStream_t stream){
  const float* x     = (const float*)d_in[0];
  const float* W_emb = (const float*)d_in[1];
  const float* b_emb = (const float*)d_in[2];
  const float* W_f   = (const float*)d_in[3];
  const float* b_f   = (const float*)d_in[4];
  const float* W_i   = (const float*)d_in[5];
  const float* b_i   = (const float*)d_in[6];
  const float* W_c   = (const float*)d_in[7];
  const float* b_c   = (const float*)d_in[8];
  const float* W_o   = (const float*)d_in[9];
  const float* b_o   = (const float*)d_in[10];
  const float* W_out = (const float*)d_in[11];
  const float* b_out = (const float*)d_in[12];
  float* out = (float*)d_out;
  uint32_t* e_ws = (uint32_t*)d_ws;    // B*T*16*4 = 16.8 MB

  const int rows = kB * kT;
  emb_kernel<<<(rows + 255) / 256, 256, 0, stream>>>(x, W_emb, b_emb, e_ws);
  lstm_kernel<<<kB, 512, 0, stream>>>(e_ws, W_f, b_f, W_i, b_i, W_c, b_c,
                                      W_o, b_o, W_out, b_out, out);
}

// Round 8
// 1660.511 us; speedup vs baseline: 1.7093x; 1.0928x over previous
//
#include <hip/hip_runtime.h>
#include <stdint.h>

namespace {
constexpr int kB = 64, kT = 4096, kDin = 64, kDe = 24, kH = 128;
constexpr int kCh = 16;                 // steps per pre-chunk
constexpr int kNCh = kT / kCh;          // 256 chunks
constexpr int kRowU = 16;               // uints per padded e row (24 f16 + 8 zero)

typedef __attribute__((ext_vector_type(8))) _Float16 frag8;   // f16 MFMA A/B
typedef __attribute__((ext_vector_type(4))) float v4f;        // MFMA C/D
typedef __attribute__((ext_vector_type(8))) int v8i;          // fp8 MFMA A/B
union H2U { uint32_t u; _Float16 s[2]; };

__device__ __forceinline__ float rcp_fast(float x){
#if __has_builtin(__builtin_amdgcn_rcpf)
  return __builtin_amdgcn_rcpf(x);
#else
  return 1.0f / x;
#endif
}
__device__ __forceinline__ float sigmoid_f(float x){
  return rcp_fast(1.0f + __expf(-x));
}
__device__ __forceinline__ float tanh_f(float x){
  return 1.0f - 2.0f * rcp_fast(1.0f + __expf(2.0f * x));
}
__device__ __forceinline__ uint32_t pack2(float lo, float hi){
  H2U u; u.s[0] = (_Float16)lo; u.s[1] = (_Float16)hi; return u.u;
}
__device__ __forceinline__ uint32_t sw_fp8(float x){   // fallback e4m3 encode
  union{float f; uint32_t u;} v; v.f = x;
  uint32_t s = (v.u >> 24) & 0x80u;
  float a = fabsf(x);
  if (a < 0.0009765625f) return s;
  if (a > 448.0f) a = 448.0f;
  int e; float m = frexpf(a, &e);
  int E = e - 1 + 7;
  uint32_t bits;
  if (E <= 0){
    int q = (int)(a * 512.0f + 0.5f); if (q > 7) q = 7; bits = (uint32_t)q;
  } else {
    int q = (int)(m * 16.0f + 0.5f);
    if (q == 16){ q = 8; ++E; }
    if (E > 15) { E = 15; q = 14; }
    bits = ((uint32_t)E << 3) | ((uint32_t)q & 7u);
  }
  return s | bits;
}
template <bool HI>
__device__ __forceinline__ uint32_t fp8pair(float a, float b, uint32_t old){
#if __has_builtin(__builtin_amdgcn_cvt_pk_fp8_f32)
  return (uint32_t)__builtin_amdgcn_cvt_pk_fp8_f32(a, b, (int)old, HI);
#else
  uint32_t p = sw_fp8(a) | (sw_fp8(b) << 8);
  return HI ? ((old & 0x0000ffffu) | (p << 16)) : ((old & 0xffff0000u) | p);
#endif
}
} // namespace

// Kernel 1 (parallel): e[b,t,:] = sigmoid(x[b,t,:] @ W_emb + b_emb), packed f16,
// rows padded to 32 f16 (last 8 = 0).
__global__ __launch_bounds__(256) void emb_kernel(
    const float* __restrict__ x, const float* __restrict__ W,
    const float* __restrict__ bias, uint32_t* __restrict__ e_out)
{
  int r = blockIdx.x * blockDim.x + threadIdx.x;
  if (r >= kB * kT) return;
  const float4* xr = (const float4*)(x + (size_t)r * kDin);
  float acc[kDe];
#pragma unroll
  for (int k = 0; k < kDe; ++k) acc[k] = bias[k];
#pragma unroll 4
  for (int d4 = 0; d4 < kDin / 4; ++d4){
    float4 xv = xr[d4];
    const float* w0 = W + (size_t)(d4 * 4) * kDe;
#pragma unroll
    for (int k = 0; k < kDe; ++k) acc[k] += xv.x * w0[k];
#pragma unroll
    for (int k = 0; k < kDe; ++k) acc[k] += xv.y * w0[kDe + k];
#pragma unroll
    for (int k = 0; k < kDe; ++k) acc[k] += xv.z * w0[2 * kDe + k];
#pragma unroll
    for (int k = 0; k < kDe; ++k) acc[k] += xv.w * w0[3 * kDe + k];
  }
  uint32_t p[12];
#pragma unroll
  for (int k = 0; k < 12; ++k)
    p[k] = pack2(sigmoid_f(acc[2 * k]), sigmoid_f(acc[2 * k + 1]));
  uint4* dst = (uint4*)(e_out + (size_t)r * kRowU);
  dst[0] = make_uint4(p[0], p[1], p[2],  p[3]);
  dst[1] = make_uint4(p[4], p[5], p[6],  p[7]);
  dst[2] = make_uint4(p[8], p[9], p[10], p[11]);
  dst[3] = make_uint4(0u, 0u, 0u, 0u);
}

// Kernel 2: one block (512 thr, 8 waves) per batch chain.
// Serial h-GEMM via MX-fp8 scaled MFMA 16x16x128 (4/wave/step). Per-chunk
// pre-activations (e-part + bias) computed by f16 MFMA into preh[g][u][s]
// (ds_write_b64, conflict-free), then prefetched into 32 VGPRs per thread
// (intra-wave, no barrier). Step chain: hfp8 read -> 4 MFMA -> nonlin ->
// h fp8 write -> barrier. One barrier per step + one per chunk boundary.
__global__ __launch_bounds__(512, 1) void lstm_kernel(
    const uint32_t* __restrict__ e_ws,
    const float* __restrict__ W_f, const float* __restrict__ b_f,
    const float* __restrict__ W_i, const float* __restrict__ b_i,
    const float* __restrict__ W_c, const float* __restrict__ b_c,
    const float* __restrict__ W_o, const float* __restrict__ b_o,
    const float* __restrict__ W_out, const float* __restrict__ b_out,
    float* __restrict__ out)
{
  __shared__ __align__(16) _Float16 preh[4 * kH * kCh];   // [g][u][s] 16 KB
  __shared__ __align__(16) uint32_t elds[kCh * kRowU];    // 1 KB e chunk (f16)
  __shared__ __align__(16) uint32_t hfp8[2 * 32];         // 2 x 128 B h (fp8 x64)
  __shared__ float red[8];

  const int b  = blockIdx.x;
  const int t0 = threadIdx.x;
  const int w  = t0 >> 6;
  const int l  = t0 & 63;
  const int q  = l >> 4;
  const int cl = l & 15;
  const int u  = w * 16 + cl;      // hidden unit owned

  const float* Wg[4] = {W_f, W_i, W_c, W_o};

  // fp8 B-frags for the h-GEMM: B[k][n]: n = u, k = q*32 + r*4 + byte,
  // W row = 24 + k, stored value = w*64 with E8M0 scale 2^-6 (code 121).
  v8i B8[4];
#pragma unroll
  for (int g = 0; g < 4; ++g){
#pragma unroll
    for (int r = 0; r < 8; ++r){
      const float* col = Wg[g] + (size_t)(24 + q * 32 + r * 4) * kH + u;
      uint32_t reg = fp8pair<false>(col[0] * 64.0f, col[kH] * 64.0f, 0u);
      reg = fp8pair<true>(col[2 * kH] * 64.0f, col[3 * kH] * 64.0f, reg);
      B8[g][r] = (int)reg;
    }
  }

  // f16 B-frags for the pre-GEMM (e-part, K=32 padded from 24)
  frag8 Bp[4];
  float biasC[4] = {b_f[u], b_i[u], b_c[u], b_o[u]};
#pragma unroll
  for (int g = 0; g < 4; ++g){
#pragma unroll
    for (int j = 0; j < 8; ++j){
      int k = q * 8 + j;
      Bp[g][j] = (_Float16)((k < kDe) ? Wg[g][(size_t)k * kH + u] : 0.0f);
    }
  }

  const uint4* e4 = (const uint4*)e_ws;          // 4 uint4 per (b,t) row
  const size_t bbase = (size_t)b * kT * 4;

  // pre-GEMM: A rows = 16 steps from elds, D[step][unit] -> preh[g][u][step]
  auto do_pregemm = [&](){
    frag8 Ae = *(const frag8*)&elds[cl * kRowU + q * 4];  // A[m=cl][k=q*8+j]
#pragma unroll
    for (int g = 0; g < 4; ++g){
      v4f c; c[0] = biasC[g]; c[1] = biasC[g]; c[2] = biasC[g]; c[3] = biasC[g];
      v4f d = __builtin_amdgcn_mfma_f32_16x16x32_f16(Ae, Bp[g], c, 0, 0, 0);
      // lane (q,cl) holds steps q*4+r for unit u -> contiguous 4 f16, b64 write
      uint32_t p0 = pack2(d[0], d[1]), p1 = pack2(d[2], d[3]);
      *(uint2*)&preh[(g * kH + u) * kCh + q * 4] = make_uint2(p0, p1);
    }
  };
  // chunk-wide C-operand prefetch: preh[g][u][0..15] -> 8 uints per gate pair
  uint32_t pb32[4][8];
  auto load_pb = [&](){
#pragma unroll
    for (int g = 0; g < 4; ++g){
      const uint4* src = (const uint4*)&preh[(g * kH + u) * kCh];
      uint4 a0 = src[0], a1 = src[1];
      pb32[g][0]=a0.x; pb32[g][1]=a0.y; pb32[g][2]=a0.z; pb32[g][3]=a0.w;
      pb32[g][4]=a1.x; pb32[g][5]=a1.y; pb32[g][6]=a1.z; pb32[g][7]=a1.w;
    }
  };

  // startup: e chunk 0 -> elds; h = 0; pre-GEMM chunk 0; prefetch chunk 1
  uint4 pre4;
  if (t0 < 64) ((uint4*)elds)[t0] = e4[bbase + t0];
  if (t0 < 32) hfp8[t0] = 0u;
  __syncthreads();
  do_pregemm();
  load_pb();
  if (t0 < 64 && kNCh > 1) pre4 = e4[bbase + (size_t)kCh * 4 + t0];

  float cst = 0.0f, h_last = 0.0f;

#pragma unroll 1
  for (int cc = 0; cc < kNCh; ++cc){
#pragma unroll
    for (int s = 0; s < kCh; ++s){
      const int cur = (cc * kCh + s) & 1, nxt = cur ^ 1;

      // A: 32 h-bytes for this lane's k-quad (uniform per quad -> broadcast)
      const uint32_t* hb = &hfp8[cur * 32];
      uint4 lo  = *(const uint4*)(hb + q * 8);
      uint4 hi4 = *(const uint4*)(hb + q * 8 + 4);
      v8i A;
      A[0] = (int)lo.x;  A[1] = (int)lo.y;  A[2] = (int)lo.z;  A[3] = (int)lo.w;
      A[4] = (int)hi4.x; A[5] = (int)hi4.y; A[6] = (int)hi4.z; A[7] = (int)hi4.w;

      v4f acc[4];
#pragma unroll
      for (int g = 0; g < 4; ++g){
        H2U pv; pv.u = pb32[g][s >> 1];
        v4f c; c[0] = (float)pv.s[s & 1]; c[1] = 0.0f; c[2] = 0.0f; c[3] = 0.0f;
        acc[g] = __builtin_amdgcn_mfma_scale_f32_16x16x128_f8f6f4(
                     A, B8[g], c, 0, 0, 0, 121, 0, 121);
      }

      float f  = sigmoid_f(acc[0][0]);
      float ig = sigmoid_f(acc[1][0]);
      float gg = tanh_f(acc[2][0]);
      float og = sigmoid_f(acc[3][0]);
      cst    = fmaf(cst, f, ig * gg);
      h_last = tanh_f(cst) * og;
      if (l < 16){
        uint32_t byte = fp8pair<false>(h_last * 64.0f, h_last * 64.0f, 0u) & 0xffu;
        ((uint8_t*)&hfp8[nxt * 32])[u] = (uint8_t)byte;
      }
      // last step of chunk: commit prefetched e before the barrier
      if (s == kCh - 1 && cc + 1 < kNCh && t0 < 64) ((uint4*)elds)[t0] = pre4;
      __syncthreads();
    }

    if (cc + 1 < kNCh){
      do_pregemm();                // reads elds (barriered), writes preh
      load_pb();                   // intra-wave, lgkmcnt only
      if (t0 < 64 && cc + 2 < kNCh)
        pre4 = e4[bbase + (size_t)(cc + 2) * kCh * 4 + t0];
    }
  }

  // epilogue: out[b] = sigmoid(h_T @ W_out + b_out)
  float partial = (l < 16) ? h_last * W_out[u] : 0.0f;
#pragma unroll
  for (int off = 1; off <= 32; off <<= 1) partial += __shfl_xor(partial, off, 64);
  if (l == 0) red[w] = partial;
  __syncthreads();
  if (t0 == 0){
    float acc = b_out[0];
#pragma unroll
    for (int k = 0; k < 8; ++k) acc += red[k];
    out[b] = sigmoid_f(acc);
  }
}

extern "C" void kernel_launch(void* const* d_in, const int* in_sizes, int n_in,
                              void* d_out, int out_size, void* d_ws, size_t ws_size,
                              hipStream_t stream){
  const float* x     = (const float*)d_in[0];
  const float* W_emb = (const float*)d_in[1];
  const float* b_emb = (const float*)d_in[2];
  const float* W_f   = (const float*)d_in[3];
  const float* b_f   = (const float*)d_in[4];
  const float* W_i   = (const float*)d_in[5];
  const float* b_i   = (const float*)d_in[6];
  const float* W_c   = (const float*)d_in[7];
  const float* b_c   = (const float*)d_in[8];
  const float* W_o   = (const float*)d_in[9];
  const float* b_o   = (const float*)d_in[10];
  const float* W_out = (const float*)d_in[11];
  const float* b_out = (const float*)d_in[12];
  float* out = (float*)d_out;
  uint32_t* e_ws = (uint32_t*)d_ws;    // B*T*16*4 = 16.8 MB

  const int rows = kB * kT;
  emb_kernel<<<(rows + 255) / 256, 256, 0, stream>>>(x, W_emb, b_emb, e_ws);
  lstm_kernel<<<kB, 512, 0, stream>>>(e_ws, W_f, b_f, W_i, b_i, W_c, b_c,
                                      W_o, b_o, W_out, b_out, out);
}

// Round 9
// 1534.668 us; speedup vs baseline: 1.8495x; 1.0820x over previous
//
#include <hip/hip_runtime.h>
#include <stdint.h>

namespace {
constexpr int kB = 64, kT = 4096, kDin = 64, kDe = 24, kH = 128;
constexpr int kCh = 16;                 // steps per pre-chunk
constexpr int kNCh = kT / kCh;          // 256 chunks
constexpr int kRowU = 16;               // uints per padded e row (24 f16 + 8 zero)
constexpr int kPS = 20;                 // preh stride per (g,u) in floats (pad 16->20)

typedef __attribute__((ext_vector_type(8))) _Float16 frag8;   // f16 MFMA A/B
typedef __attribute__((ext_vector_type(4))) float v4f;        // MFMA C/D
typedef __attribute__((ext_vector_type(8))) int v8i;          // fp8 MFMA A/B
union H2U { uint32_t u; _Float16 s[2]; };

__device__ __forceinline__ float rcp_fast(float x){
#if __has_builtin(__builtin_amdgcn_rcpf)
  return __builtin_amdgcn_rcpf(x);
#else
  return 1.0f / x;
#endif
}
__device__ __forceinline__ float sigmoid_f(float x){
  return rcp_fast(1.0f + __expf(-x));
}
__device__ __forceinline__ float tanh_f(float x){
  return 1.0f - 2.0f * rcp_fast(1.0f + __expf(2.0f * x));
}
__device__ __forceinline__ uint32_t pack2(float lo, float hi){
  H2U u; u.s[0] = (_Float16)lo; u.s[1] = (_Float16)hi; return u.u;
}
__device__ __forceinline__ uint32_t sw_fp8(float x){   // fallback e4m3 encode
  union{float f; uint32_t u;} v; v.f = x;
  uint32_t s = (v.u >> 24) & 0x80u;
  float a = fabsf(x);
  if (a < 0.0009765625f) return s;
  if (a > 448.0f) a = 448.0f;
  int e; float m = frexpf(a, &e);
  int E = e - 1 + 7;
  uint32_t bits;
  if (E <= 0){
    int q = (int)(a * 512.0f + 0.5f); if (q > 7) q = 7; bits = (uint32_t)q;
  } else {
    int q = (int)(m * 16.0f + 0.5f);
    if (q == 16){ q = 8; ++E; }
    if (E > 15) { E = 15; q = 14; }
    bits = ((uint32_t)E << 3) | ((uint32_t)q & 7u);
  }
  return s | bits;
}
template <bool HI>
__device__ __forceinline__ uint32_t fp8pair(float a, float b, uint32_t old){
#if __has_builtin(__builtin_amdgcn_cvt_pk_fp8_f32)
  return (uint32_t)__builtin_amdgcn_cvt_pk_fp8_f32(a, b, (int)old, HI);
#else
  uint32_t p = sw_fp8(a) | (sw_fp8(b) << 8);
  return HI ? ((old & 0x0000ffffu) | (p << 16)) : ((old & 0xffff0000u) | p);
#endif
}
} // namespace

// Kernel 1 (parallel): e[b,t,:] = sigmoid(x[b,t,:] @ W_emb + b_emb), packed f16,
// rows padded to 32 f16 (last 8 = 0).
__global__ __launch_bounds__(256) void emb_kernel(
    const float* __restrict__ x, const float* __restrict__ W,
    const float* __restrict__ bias, uint32_t* __restrict__ e_out)
{
  int r = blockIdx.x * blockDim.x + threadIdx.x;
  if (r >= kB * kT) return;
  const float4* xr = (const float4*)(x + (size_t)r * kDin);
  float acc[kDe];
#pragma unroll
  for (int k = 0; k < kDe; ++k) acc[k] = bias[k];
#pragma unroll 4
  for (int d4 = 0; d4 < kDin / 4; ++d4){
    float4 xv = xr[d4];
    const float* w0 = W + (size_t)(d4 * 4) * kDe;
#pragma unroll
    for (int k = 0; k < kDe; ++k) acc[k] += xv.x * w0[k];
#pragma unroll
    for (int k = 0; k < kDe; ++k) acc[k] += xv.y * w0[kDe + k];
#pragma unroll
    for (int k = 0; k < kDe; ++k) acc[k] += xv.z * w0[2 * kDe + k];
#pragma unroll
    for (int k = 0; k < kDe; ++k) acc[k] += xv.w * w0[3 * kDe + k];
  }
  uint32_t p[12];
#pragma unroll
  for (int k = 0; k < 12; ++k)
    p[k] = pack2(sigmoid_f(acc[2 * k]), sigmoid_f(acc[2 * k + 1]));
  uint4* dst = (uint4*)(e_out + (size_t)r * kRowU);
  dst[0] = make_uint4(p[0], p[1], p[2],  p[3]);
  dst[1] = make_uint4(p[4], p[5], p[6],  p[7]);
  dst[2] = make_uint4(p[8], p[9], p[10], p[11]);
  dst[3] = make_uint4(0u, 0u, 0u, 0u);
}

// Kernel 2: one block (512 thr, 8 waves) per batch chain.
// Serial h-GEMM via MX-fp8 scaled MFMA 16x16x128 (4/wave/step), C = zero;
// per-step pre-activation (e-part + bias, f32) added on the scalar side from
// registers prefetched per 16-step chunk. preh padded (stride 20 f32) ->
// conflict-free b128 LDS traffic. Step chain: v8i LDS read -> 4 MFMA ->
// add pre -> nonlin -> c/h update -> fp8 h write -> barrier.
__global__ __launch_bounds__(512, 1) void lstm_kernel(
    const uint32_t* __restrict__ e_ws,
    const float* __restrict__ W_f, const float* __restrict__ b_f,
    const float* __restrict__ W_i, const float* __restrict__ b_i,
    const float* __restrict__ W_c, const float* __restrict__ b_c,
    const float* __restrict__ W_o, const float* __restrict__ b_o,
    const float* __restrict__ W_out, const float* __restrict__ b_out,
    float* __restrict__ out)
{
  __shared__ __align__(16) float preh[4 * kH * kPS];      // 40 KB [g][u][s pad 20]
  __shared__ __align__(16) uint32_t elds[kCh * kRowU];    // 1 KB e chunk (f16)
  __shared__ __align__(64) uint32_t hfp8[2 * 32];         // 2 x 128 B h (fp8 x64)
  __shared__ float red[8];

  const int b  = blockIdx.x;
  const int t0 = threadIdx.x;
  const int w  = t0 >> 6;
  const int l  = t0 & 63;
  const int q  = l >> 4;
  const int cl = l & 15;
  const int u  = w * 16 + cl;      // hidden unit owned

  const float* Wg[4] = {W_f, W_i, W_c, W_o};

  // fp8 B-frags for the h-GEMM: B[k][n]: n = u, k = q*32 + r*4 + byte,
  // W row = 24 + k, stored value = w*64 with E8M0 scale 2^-6 (code 121).
  v8i B8[4];
#pragma unroll
  for (int g = 0; g < 4; ++g){
#pragma unroll
    for (int r = 0; r < 8; ++r){
      const float* col = Wg[g] + (size_t)(24 + q * 32 + r * 4) * kH + u;
      uint32_t reg = fp8pair<false>(col[0] * 64.0f, col[kH] * 64.0f, 0u);
      reg = fp8pair<true>(col[2 * kH] * 64.0f, col[3 * kH] * 64.0f, reg);
      B8[g][r] = (int)reg;
    }
  }

  // f16 B-frags for the pre-GEMM (e-part, K=32 padded from 24)
  frag8 Bp[4];
  float biasC[4] = {b_f[u], b_i[u], b_c[u], b_o[u]};
#pragma unroll
  for (int g = 0; g < 4; ++g){
#pragma unroll
    for (int j = 0; j < 8; ++j){
      int k = q * 8 + j;
      Bp[g][j] = (_Float16)((k < kDe) ? Wg[g][(size_t)k * kH + u] : 0.0f);
    }
  }

  const uint4* e4 = (const uint4*)e_ws;          // 4 uint4 per (b,t) row
  const size_t bbase = (size_t)b * kT * 4;

  // pre-GEMM: A rows = 16 steps from elds; D[step][unit] -> preh[g][u][step]
  auto do_pregemm = [&](){
    frag8 Ae = *(const frag8*)&elds[cl * kRowU + q * 4];  // A[m=cl][k=q*8+j]
#pragma unroll
    for (int g = 0; g < 4; ++g){
      v4f c; c[0] = biasC[g]; c[1] = biasC[g]; c[2] = biasC[g]; c[3] = biasC[g];
      v4f d = __builtin_amdgcn_mfma_f32_16x16x32_f16(Ae, Bp[g], c, 0, 0, 0);
      // lane (q,cl) holds steps q*4+r for unit u -> one aligned b128 write
      *(v4f*)&preh[(g * kH + u) * kPS + q * 4] = d;
    }
  };
  // chunk-wide pre prefetch: preh[g][u][0..15] -> 16 f32 regs per gate
  float pb[4][kCh];
  auto load_pb = [&](){
#pragma unroll
    for (int g = 0; g < 4; ++g){
      const v4f* src = (const v4f*)&preh[(g * kH + u) * kPS];
#pragma unroll
      for (int r = 0; r < 4; ++r){
        v4f t = src[r];
        pb[g][4*r+0] = t[0]; pb[g][4*r+1] = t[1];
        pb[g][4*r+2] = t[2]; pb[g][4*r+3] = t[3];
      }
    }
  };

  // startup: e chunk 0 -> elds; h = 0; pre-GEMM chunk 0; prefetch chunk 1
  uint4 pre4;
  if (t0 < 64) ((uint4*)elds)[t0] = e4[bbase + t0];
  if (t0 < 32) hfp8[t0] = 0u;
  __syncthreads();
  do_pregemm();
  load_pb();
  if (t0 < 64 && kNCh > 1) pre4 = e4[bbase + (size_t)kCh * 4 + t0];

  float cst = 0.0f, h_last = 0.0f;
  const v4f zero4 = {0.0f, 0.0f, 0.0f, 0.0f};

#pragma unroll 1
  for (int cc = 0; cc < kNCh; ++cc){
#pragma unroll
    for (int s = 0; s < kCh; ++s){
      const int cur = (cc * kCh + s) & 1, nxt = cur ^ 1;

      // A: 32 h-bytes for this lane's k-quad, direct v8i LDS load
      v8i A = *(const v8i*)&hfp8[cur * 32 + q * 8];

      v4f a0 = __builtin_amdgcn_mfma_scale_f32_16x16x128_f8f6f4(
                   A, B8[0], zero4, 0, 0, 0, 121, 0, 121);
      v4f a1 = __builtin_amdgcn_mfma_scale_f32_16x16x128_f8f6f4(
                   A, B8[1], zero4, 0, 0, 0, 121, 0, 121);
      v4f a2 = __builtin_amdgcn_mfma_scale_f32_16x16x128_f8f6f4(
                   A, B8[2], zero4, 0, 0, 0, 121, 0, 121);
      v4f a3 = __builtin_amdgcn_mfma_scale_f32_16x16x128_f8f6f4(
                   A, B8[3], zero4, 0, 0, 0, 121, 0, 121);

      float f  = sigmoid_f(a0[0] + pb[0][s]);
      float ig = sigmoid_f(a1[0] + pb[1][s]);
      float gg = tanh_f(a2[0] + pb[2][s]);
      float og = sigmoid_f(a3[0] + pb[3][s]);
      cst    = fmaf(cst, f, ig * gg);
      h_last = tanh_f(cst) * og;
      if (l < 16){
        uint32_t byte = fp8pair<false>(h_last * 64.0f, h_last * 64.0f, 0u) & 0xffu;
        ((uint8_t*)&hfp8[nxt * 32])[u] = (uint8_t)byte;
      }
      // last step of chunk: commit prefetched e before the barrier
      if (s == kCh - 1 && cc + 1 < kNCh && t0 < 64) ((uint4*)elds)[t0] = pre4;
      __syncthreads();
    }

    if (cc + 1 < kNCh){
      do_pregemm();                // reads elds (barriered), writes preh
      load_pb();                   // intra-wave, lgkmcnt only
      if (t0 < 64 && cc + 2 < kNCh)
        pre4 = e4[bbase + (size_t)(cc + 2) * kCh * 4 + t0];
    }
  }

  // epilogue: out[b] = sigmoid(h_T @ W_out + b_out)
  float partial = (l < 16) ? h_last * W_out[u] : 0.0f;
#pragma unroll
  for (int off = 1; off <= 32; off <<= 1) partial += __shfl_xor(partial, off, 64);
  if (l == 0) red[w] = partial;
  __syncthreads();
  if (t0 == 0){
    float acc = b_out[0];
#pragma unroll
    for (int k = 0; k < 8; ++k) acc += red[k];
    out[b] = sigmoid_f(acc);
  }
}

extern "C" void kernel_launch(void* const* d_in, const int* in_sizes, int n_in,
                              void* d_out, int out_size, void* d_ws, size_t ws_size,
                              hipStream_t stream){
  const float* x     = (const float*)d_in[0];
  const float* W_emb = (const float*)d_in[1];
  const float* b_emb = (const float*)d_in[2];
  const float* W_f   = (const float*)d_in[3];
  const float* b_f   = (const float*)d_in[4];
  const float* W_i   = (const float*)d_in[5];
  const float* b_i   = (const float*)d_in[6];
  const float* W_c   = (const float*)d_in[7];
  const float* b_c   = (const float*)d_in[8];
  const float* W_o   = (const float*)d_in[9];
  const float* b_o   = (const float*)d_in[10];
  const float* W_out = (const float*)d_in[11];
  const float* b_out = (const float*)d_in[12];
  float* out = (float*)d_out;
  uint32_t* e_ws = (uint32_t*)d_ws;    // B*T*16*4 = 16.8 MB

  const int rows = kB * kT;
  emb_kernel<<<(rows + 255) / 256, 256, 0, stream>>>(x, W_emb, b_emb, e_ws);
  lstm_kernel<<<kB, 512, 0, stream>>>(e_ws, W_f, b_f, W_i, b_i, W_c, b_c,
                                      W_o, b_o, W_out, b_out, out);
}